// Round 5
// baseline (344.232 us; speedup 1.0000x reference)
//
#include <hip/hip_runtime.h>
#include <hip/hip_bf16.h>
#include <math.h>

#define BB 2
#define NN 1024
#define HH 128
#define LL 3
#define SY 136   // LDS tile row stride (bf16 elems): 128+8
#define SH 520   // FFN hidden row stride
#define SX 136   // FFN input row stride
#define NPB 2    // nodes per block (node/edge kernels)

typedef __attribute__((ext_vector_type(8))) short s8v;   // 8 bf16
typedef __attribute__((ext_vector_type(4))) float f4v;   // MFMA acc
typedef unsigned short u16;

static __device__ __forceinline__ u16 f2bf(float x) {
  union { float f; unsigned u; } v; v.f = x;
  unsigned r = v.u + 0x7FFFu + ((v.u >> 16) & 1u);  // RNE
  return (u16)(r >> 16);
}
// fast tanh-form GELU (|err| vs erf-gelu ~3e-3)
static __device__ __forceinline__ float geluf(float x) {
  float x2 = x * x;
  float u2 = x * (1.5957691216f + 0.0713548163f * x2);
  float e = __expf(u2);
  float d = __builtin_amdgcn_rcpf(e + 1.0f);
  return x - x * d;
}

// load a wave's B-fragments for one 128x128 weight tile
static __device__ __forceinline__ void loadB(const u16* __restrict__ Wt, int wave, int lane,
                                             s8v B0[4], s8v B1[4]) {
  const int g = lane >> 4, q = lane & 15;
  const u16* wb0 = Wt + (wave * 32 + q) * 128 + g * 8;
  const u16* wb1 = wb0 + 16 * 128;
#pragma unroll
  for (int t = 0; t < 4; ++t) { B0[t] = *(const s8v*)(wb0 + t * 32); B1[t] = *(const s8v*)(wb1 + t * 32); }
}

// 48x128 (LDS, stride SY) with preloaded B-frags; acc pre-initialized.
static __device__ __forceinline__ void gemmA(const u16* __restrict__ A,
                                             const s8v B0[4], const s8v B1[4],
                                             int lane, f4v acc[3][2]) {
  const int g = lane >> 4, q = lane & 15;
#pragma unroll
  for (int t = 0; t < 4; ++t) {
    const u16* Ab = A + t * 32 + g * 8;
    s8v a0 = *(const s8v*)(Ab + q * SY);
    s8v a1 = *(const s8v*)(Ab + (16 + q) * SY);
    s8v a2 = *(const s8v*)(Ab + (32 + q) * SY);
    acc[0][0] = __builtin_amdgcn_mfma_f32_16x16x32_bf16(a0, B0[t], acc[0][0], 0, 0, 0);
    acc[0][1] = __builtin_amdgcn_mfma_f32_16x16x32_bf16(a0, B1[t], acc[0][1], 0, 0, 0);
    acc[1][0] = __builtin_amdgcn_mfma_f32_16x16x32_bf16(a1, B0[t], acc[1][0], 0, 0, 0);
    acc[1][1] = __builtin_amdgcn_mfma_f32_16x16x32_bf16(a1, B1[t], acc[1][1], 0, 0, 0);
    acc[2][0] = __builtin_amdgcn_mfma_f32_16x16x32_bf16(a2, B0[t], acc[2][0], 0, 0, 0);
    acc[2][1] = __builtin_amdgcn_mfma_f32_16x16x32_bf16(a2, B1[t], acc[2][1], 0, 0, 0);
  }
}

static __device__ __forceinline__ void zero_acc(f4v acc[3][2]) {
#pragma unroll
  for (int rt = 0; rt < 3; ++rt)
#pragma unroll
    for (int c = 0; c < 2; ++c) acc[rt][c] = (f4v){0.f, 0.f, 0.f, 0.f};
}

// acc(+bias, gelu) -> LDS Y bf16 (stride SY). C layout: col=lane&15, row=(lane>>4)*4+r.
static __device__ __forceinline__ void store_act(const f4v acc[3][2], u16* __restrict__ Y,
                                                 int wave, int lane, const float* __restrict__ bias) {
  const int g = lane >> 4, q = lane & 15;
#pragma unroll
  for (int c = 0; c < 2; ++c) {
    const int col = wave * 32 + c * 16 + q;
    const float bv = bias[col];
#pragma unroll
    for (int rt = 0; rt < 3; ++rt)
#pragma unroll
      for (int r = 0; r < 4; ++r) {
        const int row = rt * 16 + g * 4 + r;
        Y[row * SY + col] = f2bf(geluf(acc[rt][c][r] + bv));
      }
  }
}

// synchronous stage: hE (48x128 f32) -> bf16 LDS
static __device__ __forceinline__ void stage_hE(u16* __restrict__ dst, const float* __restrict__ src,
                                                int tid) {
  const float4* hEr = (const float4*)src;
#pragma unroll
  for (int p = 0; p < 6; ++p) {
    int i = tid + p * 256; int row = i >> 5, c = i & 31;
    float4 v = hEr[i];
    uint2 pk;
    pk.x = (unsigned)f2bf(v.x) | ((unsigned)f2bf(v.y) << 16);
    pk.y = (unsigned)f2bf(v.z) | ((unsigned)f2bf(v.w) << 16);
    *(uint2*)(dst + row * SY + c * 4) = pk;
  }
}
// write prefetched hE regs to LDS (same mapping)
static __device__ __forceinline__ void stage_regs(u16* __restrict__ dst, const float4 h[6], int tid) {
#pragma unroll
  for (int p = 0; p < 6; ++p) {
    int i = tid + p * 256; int row = i >> 5, c = i & 31;
    uint2 pk;
    pk.x = (unsigned)f2bf(h[p].x) | ((unsigned)f2bf(h[p].y) << 16);
    pk.y = (unsigned)f2bf(h[p].z) | ((unsigned)f2bf(h[p].w) << 16);
    *(uint2*)(dst + row * SY + c * 4) = pk;
  }
}

// per-node Q/P(gather) prefetch into regs
static __device__ __forceinline__ void load_pq(float pP[3][4][2], float qv[2],
                                               const float* __restrict__ Q, const float* __restrict__ P,
                                               const int* __restrict__ eidx, int bid, int bbase,
                                               int wave, int g, int q) {
  const float* Qr = Q + (size_t)bid * 128;
#pragma unroll
  for (int c = 0; c < 2; ++c) qv[c] = Qr[wave * 32 + c * 16 + q];
#pragma unroll
  for (int rt = 0; rt < 3; ++rt)
#pragma unroll
    for (int r = 0; r < 4; ++r) {
      const int row = rt * 16 + g * 4 + r;
      const int idx = eidx[bid * 48 + row];
      const float* Pr = P + (size_t)(bbase + idx) * 128 + wave * 32;
#pragma unroll
      for (int c = 0; c < 2; ++c) pP[rt][r][c] = Pr[c * 16 + q];
    }
}

// ---------------- weight/hv convert ----------------
// PRE_l [512][128]: rows 0-127 W11aT(l), 128-255 W11cT(l), 256-383 W1aT((l+1)%3), 384-511 W1cT((l+1)%3)
__global__ void conv_weights(const float* __restrict__ W1, const float* __restrict__ W2,
                             const float* __restrict__ W3, const float* __restrict__ W11,
                             const float* __restrict__ W12, const float* __restrict__ W13,
                             const float* __restrict__ Win, const float* __restrict__ Wout,
                             const float* __restrict__ hV,
                             u16* __restrict__ W1bT, u16* __restrict__ W2t,
                             u16* __restrict__ W3t, u16* __restrict__ W11bT,
                             u16* __restrict__ W12t, u16* __restrict__ W13t,
                             u16* __restrict__ Wint, u16* __restrict__ Woutt,
                             u16* __restrict__ PRE, u16* __restrict__ hv0bf) {
  const int tid = blockIdx.x * blockDim.x + threadIdx.x;
  const int nt = gridDim.x * blockDim.x;
  for (int i = tid; i < LL * 128 * 128; i += nt) {
    int l = i >> 14, rem = i & 16383;
    int k = rem >> 7, n = rem & 127;
    const int o = (l * 128 + n) * 128 + k;
    const int s = l * 16384 + k * 128 + n;
    W1bT [o] = f2bf(W1 [l * 49152 + (128 + k) * 128 + n]);
    W11bT[o] = f2bf(W11[l * 49152 + (128 + k) * 128 + n]);
    W2t [o] = f2bf(W2 [s]);
    W3t [o] = f2bf(W3 [s]);
    W12t[o] = f2bf(W12[s]);
    W13t[o] = f2bf(W13[s]);
    const int ln = (l + 1 == LL) ? 0 : l + 1;
    PRE[l * 65536 + (0 * 128 + n) * 128 + k] = f2bf(W11[l * 49152 + k * 128 + n]);
    PRE[l * 65536 + (1 * 128 + n) * 128 + k] = f2bf(W11[l * 49152 + (256 + k) * 128 + n]);
    PRE[l * 65536 + (2 * 128 + n) * 128 + k] = f2bf(W1 [ln * 49152 + k * 128 + n]);
    PRE[l * 65536 + (3 * 128 + n) * 128 + k] = f2bf(W1 [ln * 49152 + (256 + k) * 128 + n]);
  }
  for (int i = tid; i < LL * 128 * 512; i += nt) {
    int l = i / (128 * 512), rem = i - l * 128 * 512;
    int k = rem / 512, u = rem - k * 512;
    Wint[(l * 512 + u) * 128 + k] = f2bf(Win[i]);
  }
  for (int i = tid; i < LL * 512 * 128; i += nt) {
    int l = i / (512 * 128), rem = i - l * 512 * 128;
    int k = rem / 128, n = rem - k * 128;
    Woutt[(l * 128 + n) * 512 + k] = f2bf(Wout[i]);
  }
  for (int i = tid; i < BB * NN * HH; i += nt) hv0bf[i] = f2bf(hV[i]);
}

// ---------------- layer-0 node pre: Q = hv@W1a, P = hv@W1c ----------------
__global__ __launch_bounds__(256) void pre_kernel(const u16* __restrict__ hvbf,
                                                  const u16* __restrict__ Wq,
                                                  const u16* __restrict__ Wp,
                                                  float* __restrict__ Q, float* __restrict__ P) {
  __shared__ __align__(16) u16 shX[16 * SX];
  const int tid = threadIdx.x, lane = tid & 63, wave = tid >> 6;
  const int g = lane >> 4, q = lane & 15;
  const int r0 = blockIdx.x * 16;
  { int row = tid >> 4, c = tid & 15;
    *(uint4*)(shX + row * SX + c * 8) = ((const uint4*)(hvbf + (size_t)r0 * 128))[tid]; }
  __syncthreads();
  s8v af[4];
#pragma unroll
  for (int t = 0; t < 4; ++t) af[t] = *(const s8v*)(shX + q * SX + t * 32 + g * 8);
  const u16* W = (wave < 2) ? Wq : Wp;
  float* D = (wave < 2) ? Q : P;
  const int c0 = (wave & 1) * 64;
#pragma unroll
  for (int cf = 0; cf < 4; ++cf) {
    const int col = c0 + cf * 16 + q;
    const u16* wb = W + (size_t)col * 128 + g * 8;
    f4v acc = (f4v){0.f, 0.f, 0.f, 0.f};
#pragma unroll
    for (int t = 0; t < 4; ++t)
      acc = __builtin_amdgcn_mfma_f32_16x16x32_bf16(af[t], *(const s8v*)(wb + t * 32), acc, 0, 0, 0);
#pragma unroll
    for (int r = 0; r < 4; ++r) D[(size_t)(r0 + g * 4 + r) * 128 + col] = acc[r];
  }
}

// ---------------- node message: 2 nodes/block, pipelined ----------------
__global__ __launch_bounds__(256, 4) void node_msg(
    const float* __restrict__ hv_res, const float* __restrict__ Qn, const float* __restrict__ Pn,
    const float* __restrict__ hE_src, const int* __restrict__ eidx,
    const float* __restrict__ mask_att,
    const u16* __restrict__ W1bT, const u16* __restrict__ W2t, const u16* __restrict__ W3t,
    const float* __restrict__ b1, const float* __restrict__ b2, const float* __restrict__ b3,
    const float* __restrict__ g1, const float* __restrict__ be1,
    float* __restrict__ hv1, u16* __restrict__ hv1bf) {
  __shared__ __align__(16) u16 S0[48 * SY], S1[48 * SY], Yb[48 * SY];
  __shared__ float sh_mask[NPB * 48];

  const int tid = threadIdx.x, lane = tid & 63, wave = tid >> 6;
  const int g = lane >> 4, q = lane & 15;
  const int bid0 = blockIdx.x * NPB, bbase = bid0 & ~(NN - 1);

  if (tid < NPB * 48) sh_mask[tid] = mask_att[bid0 * 48 + tid];
  stage_hE(S0, hE_src + (size_t)bid0 * 6144, tid);
  float pP[3][4][2], qv[2];
  load_pq(pP, qv, Qn, Pn, eidx, bid0, bbase, wave, g, q);
  __syncthreads();

#pragma unroll
  for (int i = 0; i < NPB; ++i) {
    u16* Scur = (i == 0) ? S0 : S1;
    u16* Snxt = (i == 0) ? S1 : S0;
    const int bid = bid0 + i;

    s8v Ba[4], Bb[4];
    loadB(W1bT, wave, lane, Ba, Bb);
    f4v acc[3][2];
#pragma unroll
    for (int c = 0; c < 2; ++c)
#pragma unroll
      for (int rt = 0; rt < 3; ++rt)
#pragma unroll
        for (int r = 0; r < 4; ++r) acc[rt][c][r] = qv[c] + pP[rt][r][c];
    gemmA(Scur, Ba, Bb, lane, acc);

    float4 hpre[6];
    if (i + 1 < NPB) {
      const float4* src = (const float4*)(hE_src + (size_t)(bid + 1) * 6144);
#pragma unroll
      for (int p = 0; p < 6; ++p) hpre[p] = src[tid + p * 256];
    }
    loadB(W2t, wave, lane, Ba, Bb);
    __syncthreads();                               // bar1: GEMM1 reads done
    store_act(acc, Yb, wave, lane, b1);
    __syncthreads();                               // bar2: Y1 visible
    if (i + 1 < NPB) stage_regs(Snxt, hpre, tid);
    zero_acc(acc);
    gemmA(Yb, Ba, Bb, lane, acc);
    loadB(W3t, wave, lane, Ba, Bb);
    store_act(acc, Scur, wave, lane, b2);
    __syncthreads();                               // bar3: Y2 visible, Yb free
    zero_acc(acc);
    gemmA(Scur, Ba, Bb, lane, acc);
    if (i + 1 < NPB) load_pq(pP, qv, Qn, Pn, eidx, bid + 1, bbase, wave, g, q);

    float msum = 0.f;
#pragma unroll
    for (int k = 0; k < 48; ++k) msum += sh_mask[i * 48 + k];
    float p0 = 0.f, p1 = 0.f;
#pragma unroll
    for (int rt = 0; rt < 3; ++rt)
#pragma unroll
      for (int r = 0; r < 4; ++r) {
        const float mk = sh_mask[i * 48 + rt * 16 + g * 4 + r];
        p0 += acc[rt][0][r] * mk;
        p1 += acc[rt][1][r] * mk;
      }
    p0 += __shfl_xor(p0, 16); p0 += __shfl_xor(p0, 32);
    p1 += __shfl_xor(p1, 16); p1 += __shfl_xor(p1, 32);
    float* sh_x = (float*)Yb;          // overlay: Yb dead after bar3
    float* sh_st = (float*)Yb + 128;
    if (g == 0) {
      const int c0 = wave * 32 + q, c1 = wave * 32 + 16 + q;
      sh_x[c0] = hv_res[(size_t)bid * 128 + c0] + (p0 + b3[c0] * msum) * (1.f / 30.f);
      sh_x[c1] = hv_res[(size_t)bid * 128 + c1] + (p1 + b3[c1] * msum) * (1.f / 30.f);
    }
    __syncthreads();                               // bar4
    if (tid < 64) {
      float a = sh_x[tid], c2 = sh_x[tid + 64];
      float s = a + c2, ss = a * a + c2 * c2;
#pragma unroll
      for (int off = 32; off; off >>= 1) { s += __shfl_xor(s, off); ss += __shfl_xor(ss, off); }
      if (tid == 0) { float mu = s * (1.f / 128.f); sh_st[0] = mu; sh_st[1] = ss * (1.f / 128.f) - mu * mu; }
    }
    __syncthreads();                               // bar5
    if (tid < 128) {
      float mu = sh_st[0], rs = rsqrtf(sh_st[1] + 1e-5f);
      float v = g1[tid] * (sh_x[tid] - mu) * rs + be1[tid];
      hv1[(size_t)bid * 128 + tid] = v;
      hv1bf[(size_t)bid * 128 + tid] = f2bf(v);
    }
  }
}

// ---------------- FFN + LN2 + mask + fused pre-products ----------------
__global__ __launch_bounds__(256) void ffn_kernel(
    const float* __restrict__ hv1, const u16* __restrict__ hv1bf,
    const u16* __restrict__ Wint, const float* __restrict__ binp,
    const u16* __restrict__ Woutt, const float* __restrict__ boutp,
    const float* __restrict__ g2, const float* __restrict__ be2,
    const float* __restrict__ mask_V,
    const u16* __restrict__ PRE,
    float* __restrict__ hv2,
    float* __restrict__ Qe, float* __restrict__ Pe,
    float* __restrict__ QnN, float* __restrict__ PnN) {
  __shared__ __align__(16) u16 shX[16 * SX];
  __shared__ __align__(16) u16 shH[16 * SH];
  __shared__ float shM[8 * 128];
  const int tid = threadIdx.x, lane = tid & 63, wave = tid >> 6;
  const int g = lane >> 4, q = lane & 15;
  const int r0 = blockIdx.x * 8;

  {
    int row = tid >> 4, c = tid & 15;
    uint4 v = (uint4){0, 0, 0, 0};
    if (tid < 128) v = ((const uint4*)(hv1bf + (size_t)r0 * 128))[tid];
    *(uint4*)(shX + row * SX + c * 8) = v;
  }
  __syncthreads();

  s8v a[4];
#pragma unroll
  for (int t = 0; t < 4; ++t) a[t] = *(const s8v*)(shX + q * SX + t * 32 + g * 8);
#pragma unroll
  for (int cf = 0; cf < 8; ++cf) {
    const int u = wave * 128 + cf * 16 + q;
    const u16* wb = Wint + (size_t)u * 128 + g * 8;
    f4v acc = (f4v){0.f, 0.f, 0.f, 0.f};
#pragma unroll
    for (int t = 0; t < 4; ++t)
      acc = __builtin_amdgcn_mfma_f32_16x16x32_bf16(a[t], *(const s8v*)(wb + t * 32), acc, 0, 0, 0);
    const float bv = binp[u];
#pragma unroll
    for (int r = 0; r < 4; ++r) shH[(g * 4 + r) * SH + u] = f2bf(geluf(acc[r] + bv));
  }
  __syncthreads();

#pragma unroll
  for (int c = 0; c < 2; ++c) {
    const int col = wave * 32 + c * 16 + q;
    const u16* wb = Woutt + (size_t)col * 512 + g * 8;
    s8v Bv[16];
#pragma unroll
    for (int t = 0; t < 16; ++t) Bv[t] = *(const s8v*)(wb + t * 32);
    f4v acc = (f4v){0.f, 0.f, 0.f, 0.f};
#pragma unroll
    for (int t = 0; t < 16; ++t) {
      s8v av = *(const s8v*)(shH + q * SH + t * 32 + g * 8);
      acc = __builtin_amdgcn_mfma_f32_16x16x32_bf16(av, Bv[t], acc, 0, 0, 0);
    }
    const float bv = boutp[col];
#pragma unroll
    for (int r = 0; r < 4; ++r) {
      const int row = g * 4 + r;
      if (row < 8) shM[row * 128 + col] = acc[r] + bv;
    }
  }
  __syncthreads();

#pragma unroll
  for (int i = 0; i < 2; ++i) {
    const int row = wave * 2 + i, gr = r0 + row;
    float x0 = hv1[(size_t)gr * 128 + lane]      + shM[row * 128 + lane];
    float x1 = hv1[(size_t)gr * 128 + 64 + lane] + shM[row * 128 + 64 + lane];
    float s = x0 + x1, ss = x0 * x0 + x1 * x1;
#pragma unroll
    for (int off = 32; off; off >>= 1) { s += __shfl_xor(s, off); ss += __shfl_xor(ss, off); }
    const float mu = s * (1.f / 128.f);
    const float rs = rsqrtf(ss * (1.f / 128.f) - mu * mu + 1e-5f);
    const float mv = mask_V[gr];
    float o0 = mv * (g2[lane]      * (x0 - mu) * rs + be2[lane]);
    float o1 = mv * (g2[lane + 64] * (x1 - mu) * rs + be2[lane + 64]);
    hv2[(size_t)gr * 128 + lane] = o0;
    hv2[(size_t)gr * 128 + 64 + lane] = o1;
    shX[row * SX + lane] = f2bf(o0);
    shX[row * SX + 64 + lane] = f2bf(o1);
  }
  __syncthreads();

  s8v af[4];
#pragma unroll
  for (int t = 0; t < 4; ++t) af[t] = *(const s8v*)(shX + q * SX + t * 32 + g * 8);
  float* dst = (wave == 0) ? Qe : (wave == 1) ? Pe : (wave == 2) ? QnN : PnN;
  const u16* Wb = PRE + (size_t)(wave * 128) * 128;
#pragma unroll
  for (int cf = 0; cf < 8; ++cf) {
    const int colr = cf * 16 + q;
    const u16* wb = Wb + (size_t)colr * 128 + g * 8;
    f4v acc = (f4v){0.f, 0.f, 0.f, 0.f};
#pragma unroll
    for (int t = 0; t < 4; ++t)
      acc = __builtin_amdgcn_mfma_f32_16x16x32_bf16(af[t], *(const s8v*)(wb + t * 32), acc, 0, 0, 0);
    if (g < 2) {
#pragma unroll
      for (int r = 0; r < 4; ++r)
        dst[(size_t)(r0 + g * 4 + r) * 128 + colr] = acc[r];
    }
  }
}

// ---------------- edge update: 2 nodes/block, pipelined, LN3 direct-write ----------------
__global__ __launch_bounds__(256, 4) void edge_kernel(
    const float* __restrict__ Qe, const float* __restrict__ Pe,
    const float* __restrict__ hE_src, const int* __restrict__ eidx,
    const u16* __restrict__ W11bT, const u16* __restrict__ W12t, const u16* __restrict__ W13t,
    const float* __restrict__ b11, const float* __restrict__ b12, const float* __restrict__ b13,
    const float* __restrict__ g3, const float* __restrict__ be3,
    float* __restrict__ hE_out) {
  __shared__ __align__(16) u16 S0[48 * SY], S1[48 * SY], Yb[48 * SY];

  const int tid = threadIdx.x, lane = tid & 63, wave = tid >> 6;
  const int g = lane >> 4, q = lane & 15;
  const int bid0 = blockIdx.x * NPB, bbase = bid0 & ~(NN - 1);

  stage_hE(S0, hE_src + (size_t)bid0 * 6144, tid);
  float pP[3][4][2], qv[2];
  load_pq(pP, qv, Qe, Pe, eidx, bid0, bbase, wave, g, q);
  __syncthreads();

#pragma unroll
  for (int i = 0; i < NPB; ++i) {
    u16* Scur = (i == 0) ? S0 : S1;
    u16* Snxt = (i == 0) ? S1 : S0;
    const int bid = bid0 + i;

    s8v Ba[4], Bb[4];
    loadB(W11bT, wave, lane, Ba, Bb);
    f4v acc[3][2];
#pragma unroll
    for (int c = 0; c < 2; ++c)
#pragma unroll
      for (int rt = 0; rt < 3; ++rt)
#pragma unroll
        for (int r = 0; r < 4; ++r) acc[rt][c][r] = qv[c] + pP[rt][r][c];
    gemmA(Scur, Ba, Bb, lane, acc);

    float4 hpre[6];
    if (i + 1 < NPB) {
      const float4* src = (const float4*)(hE_src + (size_t)(bid + 1) * 6144);
#pragma unroll
      for (int p = 0; p < 6; ++p) hpre[p] = src[tid + p * 256];
    }
    loadB(W12t, wave, lane, Ba, Bb);
    __syncthreads();                               // bar1
    store_act(acc, Yb, wave, lane, b11);
    __syncthreads();                               // bar2
    if (i + 1 < NPB) stage_regs(Snxt, hpre, tid);
    zero_acc(acc);
    gemmA(Yb, Ba, Bb, lane, acc);
    loadB(W13t, wave, lane, Ba, Bb);
    store_act(acc, Scur, wave, lane, b12);
    __syncthreads();                               // bar3: Y2 visible, Yb free
    // residual preload + GEMM3
    const float* heb = hE_src + (size_t)bid * 6144;
    float xh[3][2][4];
#pragma unroll
    for (int rt = 0; rt < 3; ++rt)
#pragma unroll
      for (int c = 0; c < 2; ++c)
#pragma unroll
        for (int r = 0; r < 4; ++r)
          xh[rt][c][r] = heb[(rt * 16 + g * 4 + r) * 128 + wave * 32 + c * 16 + q];
    zero_acc(acc);
    gemmA(Scur, Ba, Bb, lane, acc);
    const float bv0 = b13[wave * 32 + q], bv1 = b13[wave * 32 + 16 + q];
#pragma unroll
    for (int rt = 0; rt < 3; ++rt)
#pragma unroll
      for (int r = 0; r < 4; ++r) {
        xh[rt][0][r] += acc[rt][0][r] + bv0;
        xh[rt][1][r] += acc[rt][1][r] + bv1;
      }
    if (i + 1 < NPB) load_pq(pP, qv, Qe, Pe, eidx, bid + 1, bbase, wave, g, q);

    // per-row stats: reduce over q (16 lanes), cross-wave via LDS overlay on Yb
    float2* stats = (float2*)Yb;          // [48][4]
    float2* statsF = stats + 192;         // [48]
#pragma unroll
    for (int rt = 0; rt < 3; ++rt)
#pragma unroll
      for (int r = 0; r < 4; ++r) {
        float s = xh[rt][0][r] + xh[rt][1][r];
        float ss = xh[rt][0][r] * xh[rt][0][r] + xh[rt][1][r] * xh[rt][1][r];
#pragma unroll
        for (int off = 1; off < 16; off <<= 1) { s += __shfl_xor(s, off); ss += __shfl_xor(ss, off); }
        if (q == 0) stats[(rt * 16 + g * 4 + r) * 4 + wave] = make_float2(s, ss);
      }
    __syncthreads();                               // bar4
    if (tid < 48) {
      float s = 0.f, ss = 0.f;
#pragma unroll
      for (int w = 0; w < 4; ++w) { float2 v = stats[tid * 4 + w]; s += v.x; ss += v.y; }
      float mu = s * (1.f / 128.f);
      float rs = rsqrtf(ss * (1.f / 128.f) - mu * mu + 1e-5f);
      statsF[tid] = make_float2(mu, rs);
    }
    __syncthreads();                               // bar5
    float* hob = hE_out + (size_t)bid * 6144;
    const float g30 = g3[wave * 32 + q], g31 = g3[wave * 32 + 16 + q];
    const float be30 = be3[wave * 32 + q], be31 = be3[wave * 32 + 16 + q];
#pragma unroll
    for (int rt = 0; rt < 3; ++rt)
#pragma unroll
      for (int r = 0; r < 4; ++r) {
        const int row = rt * 16 + g * 4 + r;
        const float2 mf = statsF[row];
        hob[row * 128 + wave * 32 + q]      = g30 * (xh[rt][0][r] - mf.x) * mf.y + be30;
        hob[row * 128 + wave * 32 + 16 + q] = g31 * (xh[rt][1][r] - mf.x) * mf.y + be31;
      }
  }
}

extern "C" void kernel_launch(void* const* d_in, const int* in_sizes, int n_in,
                              void* d_out, int out_size, void* d_ws, size_t ws_size,
                              hipStream_t stream) {
  const float* h_V      = (const float*)d_in[0];
  const float* h_E      = (const float*)d_in[1];
  const int*   E_idx    = (const int*)d_in[2];
  const float* mask_V   = (const float*)d_in[3];
  const float* mask_att = (const float*)d_in[4];
  const float* W1   = (const float*)d_in[5];   const float* b1   = (const float*)d_in[6];
  const float* W2   = (const float*)d_in[7];   const float* b2   = (const float*)d_in[8];
  const float* W3   = (const float*)d_in[9];   const float* b3   = (const float*)d_in[10];
  const float* W11  = (const float*)d_in[11];  const float* b11  = (const float*)d_in[12];
  const float* W12  = (const float*)d_in[13];  const float* b12  = (const float*)d_in[14];
  const float* W13  = (const float*)d_in[15];  const float* b13  = (const float*)d_in[16];
  const float* Win  = (const float*)d_in[17];  const float* binp = (const float*)d_in[18];
  const float* Wout = (const float*)d_in[19];  const float* boutp= (const float*)d_in[20];
  const float* g1   = (const float*)d_in[21];  const float* be1  = (const float*)d_in[22];
  const float* g2   = (const float*)d_in[23];  const float* be2  = (const float*)d_in[24];
  const float* g3   = (const float*)d_in[25];  const float* be3  = (const float*)d_in[26];

  float* outV = (float*)d_out;                 // [2,1024,128]
  float* outE = outV + (size_t)BB * NN * HH;   // [2,1024,48,128]

  u16* ws     = (u16*)d_ws;
  u16* W1bT   = ws;
  u16* W11bT  = W1bT  + 3 * 16384;
  u16* W2t    = W11bT + 3 * 16384;
  u16* W3t    = W2t   + 3 * 16384;
  u16* W12t   = W3t   + 3 * 16384;
  u16* W13t   = W12t  + 3 * 16384;
  u16* Wint   = W13t  + 3 * 16384;
  u16* Woutt  = Wint  + 3 * 65536;
  u16* PREb   = Woutt + 3 * 65536;
  u16* hv0bf  = PREb  + 3 * 65536;
  u16* Pbf    = hv0bf + BB * NN * HH;
  float* Pf   = (float*)(Pbf + BB * NN * HH);
  float* Qf   = Pf  + BB * NN * HH;
  float* Qn   = Qf  + BB * NN * HH;
  float* Pn   = Qn  + BB * NN * HH;
  float* Qe   = Pn  + BB * NN * HH;
  float* Pe   = Qe  + BB * NN * HH;

  conv_weights<<<512, 256, 0, stream>>>(W1, W2, W3, W11, W12, W13, Win, Wout, h_V,
                                        W1bT, W2t, W3t, W11bT, W12t, W13t, Wint, Woutt,
                                        PREb, hv0bf);

  pre_kernel<<<(BB * NN) / 16, 256, 0, stream>>>(
      hv0bf, PREb + 2 * 65536 + 2 * 16384, PREb + 2 * 65536 + 3 * 16384, Qn, Pn);

  for (int l = 0; l < LL; ++l) {
    const float* hv_res  = (l == 0) ? h_V : Qf;
    const float* hE_src  = (l == 0) ? h_E : outE;
    float*       hv2_dst = (l == 2) ? outV : Qf;

    node_msg<<<(BB * NN) / NPB, 256, 0, stream>>>(
        hv_res, Qn, Pn, hE_src, E_idx, mask_att,
        W1bT + l * 16384, W2t + l * 16384, W3t + l * 16384,
        b1 + l * 128, b2 + l * 128, b3 + l * 128,
        g1 + l * 128, be1 + l * 128,
        Pf, Pbf);

    ffn_kernel<<<(BB * NN) / 8, 256, 0, stream>>>(
        Pf, Pbf,
        Wint + l * 65536, binp + l * 512,
        Woutt + l * 65536, boutp + l * 128,
        g2 + l * 128, be2 + l * 128, mask_V,
        PREb + l * 65536,
        hv2_dst, Qe, Pe, Qn, Pn);

    edge_kernel<<<(BB * NN) / NPB, 256, 0, stream>>>(
        Qe, Pe, hE_src, E_idx,
        W11bT + l * 16384, W12t + l * 16384, W13t + l * 16384,
        b11 + l * 128, b12 + l * 128, b13 + l * 128,
        g3 + l * 128, be3 + l * 128,
        outE);
  }
}

// Round 8
// 311.929 us; speedup vs baseline: 1.1036x; 1.1036x over previous
//
#include <hip/hip_runtime.h>
#include <hip/hip_bf16.h>
#include <math.h>

#define BB 2
#define NN 1024
#define HH 128
#define LL 3
#define SY 136   // LDS tile row stride (bf16 elems): 128+8
#define SH 520   // FFN hidden row stride
#define SX 136   // FFN input row stride
#define SM 132   // edge M f32 row stride

typedef __attribute__((ext_vector_type(8))) short s8v;   // 8 bf16
typedef __attribute__((ext_vector_type(4))) float f4v;   // MFMA acc
typedef unsigned short u16;

static __device__ __forceinline__ u16 f2bf(float x) {
  union { float f; unsigned u; } v; v.f = x;
  unsigned r = v.u + 0x7FFFu + ((v.u >> 16) & 1u);  // RNE
  return (u16)(r >> 16);
}
// fast tanh-form GELU (|err| vs erf-gelu ~3e-3)
static __device__ __forceinline__ float geluf(float x) {
  float x2 = x * x;
  float u2 = x * (1.5957691216f + 0.0713548163f * x2);
  float e = __expf(u2);
  float d = __builtin_amdgcn_rcpf(e + 1.0f);
  return x - x * d;
}

// ---- node-path helpers (R7-validated) ----
static __device__ __forceinline__ void loadB(const u16* __restrict__ Wt, int wave, int lane,
                                             s8v B0[4], s8v B1[4]) {
  const int g = lane >> 4, q = lane & 15;
  const u16* wb0 = Wt + (wave * 32 + q) * 128 + g * 8;
  const u16* wb1 = wb0 + 16 * 128;
#pragma unroll
  for (int t = 0; t < 4; ++t) { B0[t] = *(const s8v*)(wb0 + t * 32); B1[t] = *(const s8v*)(wb1 + t * 32); }
}

static __device__ __forceinline__ void gemmA(const u16* __restrict__ A,
                                             const s8v B0[4], const s8v B1[4],
                                             int lane, f4v acc[3][2]) {
  const int g = lane >> 4, q = lane & 15;
  __builtin_amdgcn_s_setprio(1);
#pragma unroll
  for (int t = 0; t < 4; ++t) {
    const u16* Ab = A + t * 32 + g * 8;
    s8v a0 = *(const s8v*)(Ab + q * SY);
    s8v a1 = *(const s8v*)(Ab + (16 + q) * SY);
    s8v a2 = *(const s8v*)(Ab + (32 + q) * SY);
    acc[0][0] = __builtin_amdgcn_mfma_f32_16x16x32_bf16(a0, B0[t], acc[0][0], 0, 0, 0);
    acc[0][1] = __builtin_amdgcn_mfma_f32_16x16x32_bf16(a0, B1[t], acc[0][1], 0, 0, 0);
    acc[1][0] = __builtin_amdgcn_mfma_f32_16x16x32_bf16(a1, B0[t], acc[1][0], 0, 0, 0);
    acc[1][1] = __builtin_amdgcn_mfma_f32_16x16x32_bf16(a1, B1[t], acc[1][1], 0, 0, 0);
    acc[2][0] = __builtin_amdgcn_mfma_f32_16x16x32_bf16(a2, B0[t], acc[2][0], 0, 0, 0);
    acc[2][1] = __builtin_amdgcn_mfma_f32_16x16x32_bf16(a2, B1[t], acc[2][1], 0, 0, 0);
  }
  __builtin_amdgcn_s_setprio(0);
}

// ---- edge-path GEMM (R4-validated: loadB inside, no setprio) ----
static __device__ __forceinline__ void gemm48k128(const u16* __restrict__ A,
                                                  const u16* __restrict__ Wt,
                                                  int wave, int lane, f4v acc[3][2]) {
  const int g = lane >> 4, q = lane & 15;
  s8v B0[4], B1[4];
  const u16* wb0 = Wt + (wave * 32 + q) * 128 + g * 8;
  const u16* wb1 = wb0 + 16 * 128;
#pragma unroll
  for (int t = 0; t < 4; ++t) { B0[t] = *(const s8v*)(wb0 + t * 32); B1[t] = *(const s8v*)(wb1 + t * 32); }
#pragma unroll
  for (int t = 0; t < 4; ++t) {
    const u16* Ab = A + t * 32 + g * 8;
    s8v a0 = *(const s8v*)(Ab + q * SY);
    s8v a1 = *(const s8v*)(Ab + (16 + q) * SY);
    s8v a2 = *(const s8v*)(Ab + (32 + q) * SY);
    acc[0][0] = __builtin_amdgcn_mfma_f32_16x16x32_bf16(a0, B0[t], acc[0][0], 0, 0, 0);
    acc[0][1] = __builtin_amdgcn_mfma_f32_16x16x32_bf16(a0, B1[t], acc[0][1], 0, 0, 0);
    acc[1][0] = __builtin_amdgcn_mfma_f32_16x16x32_bf16(a1, B0[t], acc[1][0], 0, 0, 0);
    acc[1][1] = __builtin_amdgcn_mfma_f32_16x16x32_bf16(a1, B1[t], acc[1][1], 0, 0, 0);
    acc[2][0] = __builtin_amdgcn_mfma_f32_16x16x32_bf16(a2, B0[t], acc[2][0], 0, 0, 0);
    acc[2][1] = __builtin_amdgcn_mfma_f32_16x16x32_bf16(a2, B1[t], acc[2][1], 0, 0, 0);
  }
}

static __device__ __forceinline__ void zero_acc(f4v acc[3][2]) {
#pragma unroll
  for (int rt = 0; rt < 3; ++rt)
#pragma unroll
    for (int c = 0; c < 2; ++c) acc[rt][c] = (f4v){0.f, 0.f, 0.f, 0.f};
}

// acc(+bias, gelu) -> LDS Y bf16 (stride SY). C layout: col=lane&15, row=(lane>>4)*4+r.
static __device__ __forceinline__ void store_act(const f4v acc[3][2], u16* __restrict__ Y,
                                                 int wave, int lane, const float* __restrict__ bias) {
  const int g = lane >> 4, q = lane & 15;
#pragma unroll
  for (int c = 0; c < 2; ++c) {
    const int col = wave * 32 + c * 16 + q;
    const float bv = bias[col];
#pragma unroll
    for (int rt = 0; rt < 3; ++rt)
#pragma unroll
      for (int r = 0; r < 4; ++r) {
        const int row = rt * 16 + g * 4 + r;
        Y[row * SY + col] = f2bf(geluf(acc[rt][c][r] + bv));
      }
  }
}

// stage hE f32 (48x128) -> bf16 LDS
static __device__ __forceinline__ void stage_f32(u16* __restrict__ dst, const float* src, int tid) {
  const float4* hEr = (const float4*)src;
#pragma unroll
  for (int p = 0; p < 6; ++p) {
    int i = tid + p * 256; int row = i >> 5, c = i & 31;
    float4 v = hEr[i];
    uint2 pk;
    pk.x = (unsigned)f2bf(v.x) | ((unsigned)f2bf(v.y) << 16);
    pk.y = (unsigned)f2bf(v.z) | ((unsigned)f2bf(v.w) << 16);
    *(uint2*)(dst + row * SY + c * 4) = pk;
  }
}

// acc init = Q[bid][col] + P[gather(row)][col]  (node path; reads eidx directly)
static __device__ __forceinline__ void init_acc(f4v acc[3][2],
                                                const float* __restrict__ Q, const float* __restrict__ P,
                                                const int* __restrict__ eidx, int bid, int bbase,
                                                int wave, int g, int q) {
  const float* Qr = Q + (size_t)bid * 128;
  const float qv0 = Qr[wave * 32 + q];
  const float qv1 = Qr[wave * 32 + 16 + q];
#pragma unroll
  for (int rt = 0; rt < 3; ++rt)
#pragma unroll
    for (int r = 0; r < 4; ++r) {
      const int row = rt * 16 + g * 4 + r;
      const int idx = eidx[bid * 48 + row];
      const float* Pr = P + (size_t)(bbase + idx) * 128 + wave * 32;
      acc[rt][0][r] = qv0 + Pr[q];
      acc[rt][1][r] = qv1 + Pr[16 + q];
    }
}

// ---------------- weight/hv convert ----------------
// PRE_l [512][128]: rows 0-127 W11aT(l), 128-255 W11cT(l), 256-383 W1aT((l+1)%3), 384-511 W1cT((l+1)%3)
__global__ void conv_weights(const float* __restrict__ W1, const float* __restrict__ W2,
                             const float* __restrict__ W3, const float* __restrict__ W11,
                             const float* __restrict__ W12, const float* __restrict__ W13,
                             const float* __restrict__ Win, const float* __restrict__ Wout,
                             const float* __restrict__ hV,
                             u16* __restrict__ W1bT, u16* __restrict__ W2t,
                             u16* __restrict__ W3t, u16* __restrict__ W11bT,
                             u16* __restrict__ W12t, u16* __restrict__ W13t,
                             u16* __restrict__ Wint, u16* __restrict__ Woutt,
                             u16* __restrict__ PRE, u16* __restrict__ hv0bf) {
  const int tid = blockIdx.x * blockDim.x + threadIdx.x;
  const int nt = gridDim.x * blockDim.x;
  for (int i = tid; i < LL * 128 * 128; i += nt) {
    int l = i >> 14, rem = i & 16383;
    int k = rem >> 7, n = rem & 127;
    const int o = (l * 128 + n) * 128 + k;
    const int s = l * 16384 + k * 128 + n;
    W1bT [o] = f2bf(W1 [l * 49152 + (128 + k) * 128 + n]);
    W11bT[o] = f2bf(W11[l * 49152 + (128 + k) * 128 + n]);
    W2t [o] = f2bf(W2 [s]);
    W3t [o] = f2bf(W3 [s]);
    W12t[o] = f2bf(W12[s]);
    W13t[o] = f2bf(W13[s]);
    const int ln = (l + 1 == LL) ? 0 : l + 1;
    PRE[l * 65536 + (0 * 128 + n) * 128 + k] = f2bf(W11[l * 49152 + k * 128 + n]);
    PRE[l * 65536 + (1 * 128 + n) * 128 + k] = f2bf(W11[l * 49152 + (256 + k) * 128 + n]);
    PRE[l * 65536 + (2 * 128 + n) * 128 + k] = f2bf(W1 [ln * 49152 + k * 128 + n]);
    PRE[l * 65536 + (3 * 128 + n) * 128 + k] = f2bf(W1 [ln * 49152 + (256 + k) * 128 + n]);
  }
  for (int i = tid; i < LL * 128 * 512; i += nt) {
    int l = i / (128 * 512), rem = i - l * 128 * 512;
    int k = rem / 512, u = rem - k * 512;
    Wint[(l * 512 + u) * 128 + k] = f2bf(Win[i]);
  }
  for (int i = tid; i < LL * 512 * 128; i += nt) {
    int l = i / (512 * 128), rem = i - l * 512 * 128;
    int k = rem / 128, n = rem - k * 128;
    Woutt[(l * 128 + n) * 512 + k] = f2bf(Wout[i]);
  }
  for (int i = tid; i < BB * NN * HH; i += nt) hv0bf[i] = f2bf(hV[i]);
}

// ---------------- layer-0 node pre: Q = hv@W1a, P = hv@W1c ----------------
__global__ __launch_bounds__(256) void pre_kernel(const u16* __restrict__ hvbf,
                                                  const u16* __restrict__ Wq,
                                                  const u16* __restrict__ Wp,
                                                  float* __restrict__ Q, float* __restrict__ P) {
  __shared__ __align__(16) u16 shX[16 * SX];
  const int tid = threadIdx.x, lane = tid & 63, wave = tid >> 6;
  const int g = lane >> 4, q = lane & 15;
  const int r0 = blockIdx.x * 16;
  { int row = tid >> 4, c = tid & 15;
    *(uint4*)(shX + row * SX + c * 8) = ((const uint4*)(hvbf + (size_t)r0 * 128))[tid]; }
  __syncthreads();
  s8v af[4];
#pragma unroll
  for (int t = 0; t < 4; ++t) af[t] = *(const s8v*)(shX + q * SX + t * 32 + g * 8);
  const u16* W = (wave < 2) ? Wq : Wp;
  float* D = (wave < 2) ? Q : P;
  const int c0 = (wave & 1) * 64;
#pragma unroll
  for (int cf = 0; cf < 4; ++cf) {
    const int col = c0 + cf * 16 + q;
    const u16* wb = W + (size_t)col * 128 + g * 8;
    f4v acc = (f4v){0.f, 0.f, 0.f, 0.f};
#pragma unroll
    for (int t = 0; t < 4; ++t)
      acc = __builtin_amdgcn_mfma_f32_16x16x32_bf16(af[t], *(const s8v*)(wb + t * 32), acc, 0, 0, 0);
#pragma unroll
    for (int r = 0; r < 4; ++r) D[(size_t)(r0 + g * 4 + r) * 128 + col] = acc[r];
  }
}

// ---------------- node message (R7 version — validated by h_V pass) ----------------
__global__ __launch_bounds__(256, 6) void node_msg(
    const float* __restrict__ hv_res, const float* __restrict__ Qn, const float* __restrict__ Pn,
    const float* hE_src, const int* __restrict__ eidx, const float* __restrict__ mask_att,
    const u16* __restrict__ W1bT, const u16* __restrict__ W2t, const u16* __restrict__ W3t,
    const float* __restrict__ b1, const float* __restrict__ b2, const float* __restrict__ b3,
    const float* __restrict__ g1, const float* __restrict__ be1,
    float* __restrict__ hv1, u16* __restrict__ hv1bf) {
  __shared__ __align__(16) u16 buf[2 * 48 * SY];
  __shared__ float sh_mask[48];
  __shared__ float sh_x[128];
  __shared__ float sh_st[2];
  u16* bufA = buf;
  u16* bufB = buf + 48 * SY;

  const int tid = threadIdx.x, lane = tid & 63, wave = tid >> 6;
  const int g = lane >> 4, q = lane & 15;
  const int bid = blockIdx.x, bbase = bid & ~(NN - 1);

  if (tid < 48) sh_mask[tid] = mask_att[bid * 48 + tid];
  f4v acc[3][2];
  init_acc(acc, Qn, Pn, eidx, bid, bbase, wave, g, q);
  stage_f32(bufA, hE_src + (size_t)bid * 6144, tid);
  s8v Ba[4], Bb[4];
  loadB(W1bT, wave, lane, Ba, Bb);
  __syncthreads();

  gemmA(bufA, Ba, Bb, lane, acc);
  loadB(W2t, wave, lane, Ba, Bb);
  store_act(acc, bufB, wave, lane, b1);
  __syncthreads();

  zero_acc(acc);
  gemmA(bufB, Ba, Bb, lane, acc);
  loadB(W3t, wave, lane, Ba, Bb);
  store_act(acc, bufA, wave, lane, b2);
  __syncthreads();

  zero_acc(acc);
  gemmA(bufA, Ba, Bb, lane, acc);

  float msum = 0.f;
#pragma unroll
  for (int k = 0; k < 48; ++k) msum += sh_mask[k];
  float p0 = 0.f, p1 = 0.f;
#pragma unroll
  for (int rt = 0; rt < 3; ++rt)
#pragma unroll
    for (int r = 0; r < 4; ++r) {
      const float mk = sh_mask[rt * 16 + g * 4 + r];
      p0 += acc[rt][0][r] * mk;
      p1 += acc[rt][1][r] * mk;
    }
  p0 += __shfl_xor(p0, 16); p0 += __shfl_xor(p0, 32);
  p1 += __shfl_xor(p1, 16); p1 += __shfl_xor(p1, 32);
  if (g == 0) {
    const int c0 = wave * 32 + q, c1 = wave * 32 + 16 + q;
    sh_x[c0] = hv_res[(size_t)bid * 128 + c0] + (p0 + b3[c0] * msum) * (1.f / 30.f);
    sh_x[c1] = hv_res[(size_t)bid * 128 + c1] + (p1 + b3[c1] * msum) * (1.f / 30.f);
  }
  __syncthreads();

  if (tid < 64) {
    float a = sh_x[tid], c2 = sh_x[tid + 64];
    float s = a + c2, ss = a * a + c2 * c2;
#pragma unroll
    for (int off = 32; off; off >>= 1) { s += __shfl_xor(s, off); ss += __shfl_xor(ss, off); }
    if (tid == 0) { float mu = s * (1.f / 128.f); sh_st[0] = mu; sh_st[1] = ss * (1.f / 128.f) - mu * mu; }
  }
  __syncthreads();
  if (tid < 128) {
    float mu = sh_st[0], rs = rsqrtf(sh_st[1] + 1e-5f);
    float v = g1[tid] * (sh_x[tid] - mu) * rs + be1[tid];
    hv1[(size_t)bid * 128 + tid] = v;
    hv1bf[(size_t)bid * 128 + tid] = f2bf(v);
  }
}

// ---------------- FFN + LN2 + mask + fused pre-products (validated) ----------------
__global__ __launch_bounds__(256) void ffn_kernel(
    const float* __restrict__ hv1, const u16* __restrict__ hv1bf,
    const u16* __restrict__ Wint, const float* __restrict__ binp,
    const u16* __restrict__ Woutt, const float* __restrict__ boutp,
    const float* __restrict__ g2, const float* __restrict__ be2,
    const float* __restrict__ mask_V,
    const u16* __restrict__ PRE,
    float* __restrict__ hv2,
    float* __restrict__ Qe, float* __restrict__ Pe,
    float* __restrict__ QnN, float* __restrict__ PnN) {
  __shared__ __align__(16) u16 shX[16 * SX];
  __shared__ __align__(16) u16 shH[16 * SH];
  __shared__ float shM[8 * 128];
  const int tid = threadIdx.x, lane = tid & 63, wave = tid >> 6;
  const int g = lane >> 4, q = lane & 15;
  const int r0 = blockIdx.x * 8;

  {
    int row = tid >> 4, c = tid & 15;
    uint4 v = (uint4){0, 0, 0, 0};
    if (tid < 128) v = ((const uint4*)(hv1bf + (size_t)r0 * 128))[tid];
    *(uint4*)(shX + row * SX + c * 8) = v;
  }
  __syncthreads();

  s8v a[4];
#pragma unroll
  for (int t = 0; t < 4; ++t) a[t] = *(const s8v*)(shX + q * SX + t * 32 + g * 8);
#pragma unroll
  for (int cf = 0; cf < 8; ++cf) {
    const int u = wave * 128 + cf * 16 + q;
    const u16* wb = Wint + (size_t)u * 128 + g * 8;
    f4v acc = (f4v){0.f, 0.f, 0.f, 0.f};
#pragma unroll
    for (int t = 0; t < 4; ++t)
      acc = __builtin_amdgcn_mfma_f32_16x16x32_bf16(a[t], *(const s8v*)(wb + t * 32), acc, 0, 0, 0);
    const float bv = binp[u];
#pragma unroll
    for (int r = 0; r < 4; ++r) shH[(g * 4 + r) * SH + u] = f2bf(geluf(acc[r] + bv));
  }
  __syncthreads();

#pragma unroll
  for (int c = 0; c < 2; ++c) {
    const int col = wave * 32 + c * 16 + q;
    const u16* wb = Woutt + (size_t)col * 512 + g * 8;
    s8v Bv[16];
#pragma unroll
    for (int t = 0; t < 16; ++t) Bv[t] = *(const s8v*)(wb + t * 32);
    f4v acc = (f4v){0.f, 0.f, 0.f, 0.f};
#pragma unroll
    for (int t = 0; t < 16; ++t) {
      s8v av = *(const s8v*)(shH + q * SH + t * 32 + g * 8);
      acc = __builtin_amdgcn_mfma_f32_16x16x32_bf16(av, Bv[t], acc, 0, 0, 0);
    }
    const float bv = boutp[col];
#pragma unroll
    for (int r = 0; r < 4; ++r) {
      const int row = g * 4 + r;
      if (row < 8) shM[row * 128 + col] = acc[r] + bv;
    }
  }
  __syncthreads();

#pragma unroll
  for (int i = 0; i < 2; ++i) {
    const int row = wave * 2 + i, gr = r0 + row;
    float x0 = hv1[(size_t)gr * 128 + lane]      + shM[row * 128 + lane];
    float x1 = hv1[(size_t)gr * 128 + 64 + lane] + shM[row * 128 + 64 + lane];
    float s = x0 + x1, ss = x0 * x0 + x1 * x1;
#pragma unroll
    for (int off = 32; off; off >>= 1) { s += __shfl_xor(s, off); ss += __shfl_xor(ss, off); }
    const float mu = s * (1.f / 128.f);
    const float rs = rsqrtf(ss * (1.f / 128.f) - mu * mu + 1e-5f);
    const float mv = mask_V[gr];
    float o0 = mv * (g2[lane]      * (x0 - mu) * rs + be2[lane]);
    float o1 = mv * (g2[lane + 64] * (x1 - mu) * rs + be2[lane + 64]);
    hv2[(size_t)gr * 128 + lane] = o0;
    hv2[(size_t)gr * 128 + 64 + lane] = o1;
    shX[row * SX + lane] = f2bf(o0);
    shX[row * SX + 64 + lane] = f2bf(o1);
  }
  __syncthreads();

  s8v af[4];
#pragma unroll
  for (int t = 0; t < 4; ++t) af[t] = *(const s8v*)(shX + q * SX + t * 32 + g * 8);
  float* dst = (wave == 0) ? Qe : (wave == 1) ? Pe : (wave == 2) ? QnN : PnN;
  const u16* Wb = PRE + (size_t)(wave * 128) * 128;
#pragma unroll
  for (int cf = 0; cf < 8; ++cf) {
    const int colr = cf * 16 + q;
    const u16* wb = Wb + (size_t)colr * 128 + g * 8;
    f4v acc = (f4v){0.f, 0.f, 0.f, 0.f};
#pragma unroll
    for (int t = 0; t < 4; ++t)
      acc = __builtin_amdgcn_mfma_f32_16x16x32_bf16(af[t], *(const s8v*)(wb + t * 32), acc, 0, 0, 0);
    if (g < 2) {
#pragma unroll
      for (int r = 0; r < 4; ++r)
        dst[(size_t)(r0 + g * 4 + r) * 128 + colr] = acc[r];
    }
  }
}

// ---------------- edge update (R4 version verbatim — validated @56us) ----------------
__global__ __launch_bounds__(256, 6) void edge_kernel(
    const float* __restrict__ Qe, const float* __restrict__ Pe,
    const float* hE_src, const int* __restrict__ eidx,
    const u16* __restrict__ W11bT, const u16* __restrict__ W12t, const u16* __restrict__ W13t,
    const float* __restrict__ b11, const float* __restrict__ b12, const float* __restrict__ b13,
    const float* __restrict__ g3, const float* __restrict__ be3,
    float* hE_out) {
  __shared__ __align__(16) u16 buf[2 * 48 * SY];
  __shared__ int sh_idx[48];
  u16* bufA = buf;
  u16* bufB = buf + 48 * SY;

  const int tid = threadIdx.x, lane = tid & 63, wave = tid >> 6;
  const int g = lane >> 4, q = lane & 15;
  const int bid = blockIdx.x, bbase = bid & ~(NN - 1);

  if (tid < 48) sh_idx[tid] = eidx[bid * 48 + tid];
  stage_f32(bufA, hE_src + (size_t)bid * 6144, tid);
  __syncthreads();

  f4v acc[3][2];
  {
    const float* Qr = Qe + (size_t)bid * 128;
#pragma unroll
    for (int c = 0; c < 2; ++c) {
      const int col = wave * 32 + c * 16 + q;
      const float qv = Qr[col];
#pragma unroll
      for (int rt = 0; rt < 3; ++rt)
#pragma unroll
        for (int r = 0; r < 4; ++r) {
          const int row = rt * 16 + g * 4 + r;
          acc[rt][c][r] = qv + Pe[(size_t)(bbase + sh_idx[row]) * 128 + col];
        }
    }
  }
  gemm48k128(bufA, W11bT, wave, lane, acc);
  store_act(acc, bufB, wave, lane, b11);
  __syncthreads();

  zero_acc(acc);
  gemm48k128(bufB, W12t, wave, lane, acc);
  store_act(acc, bufA, wave, lane, b12);
  __syncthreads();

  zero_acc(acc);
  gemm48k128(bufA, W13t, wave, lane, acc);
  __syncthreads();   // all waves done reading bufA/bufB; both buffers dead

  float* shMf = (float*)buf;   // 48*SM*4 = 25344 B <= 26112 B
#pragma unroll
  for (int c = 0; c < 2; ++c) {
    const int col = wave * 32 + c * 16 + q;
    const float bv = b13[col];
#pragma unroll
    for (int rt = 0; rt < 3; ++rt)
#pragma unroll
      for (int r = 0; r < 4; ++r)
        shMf[(rt * 16 + g * 4 + r) * SM + col] = acc[rt][c][r] + bv;
  }
  __syncthreads();

  const float* heb = hE_src + (size_t)bid * 6144;
  float* hob = hE_out + (size_t)bid * 6144;
#pragma unroll 1
  for (int i = 0; i < 12; ++i) {
    const int row = wave * 12 + i;
    float x0 = heb[row * 128 + lane]      + shMf[row * SM + lane];
    float x1 = heb[row * 128 + 64 + lane] + shMf[row * SM + 64 + lane];
    float s = x0 + x1, ss = x0 * x0 + x1 * x1;
#pragma unroll
    for (int off = 32; off; off >>= 1) { s += __shfl_xor(s, off); ss += __shfl_xor(ss, off); }
    const float mu = s * (1.f / 128.f);
    const float rs = rsqrtf(ss * (1.f / 128.f) - mu * mu + 1e-5f);
    hob[row * 128 + lane]      = g3[lane]      * (x0 - mu) * rs + be3[lane];
    hob[row * 128 + 64 + lane] = g3[lane + 64] * (x1 - mu) * rs + be3[lane + 64];
  }
}

extern "C" void kernel_launch(void* const* d_in, const int* in_sizes, int n_in,
                              void* d_out, int out_size, void* d_ws, size_t ws_size,
                              hipStream_t stream) {
  const float* h_V      = (const float*)d_in[0];
  const float* h_E      = (const float*)d_in[1];
  const int*   E_idx    = (const int*)d_in[2];
  const float* mask_V   = (const float*)d_in[3];
  const float* mask_att = (const float*)d_in[4];
  const float* W1   = (const float*)d_in[5];   const float* b1   = (const float*)d_in[6];
  const float* W2   = (const float*)d_in[7];   const float* b2   = (const float*)d_in[8];
  const float* W3   = (const float*)d_in[9];   const float* b3   = (const float*)d_in[10];
  const float* W11  = (const float*)d_in[11];  const float* b11  = (const float*)d_in[12];
  const float* W12  = (const float*)d_in[13];  const float* b12  = (const float*)d_in[14];
  const float* W13  = (const float*)d_in[15];  const float* b13  = (const float*)d_in[16];
  const float* Win  = (const float*)d_in[17];  const float* binp = (const float*)d_in[18];
  const float* Wout = (const float*)d_in[19];  const float* boutp= (const float*)d_in[20];
  const float* g1   = (const float*)d_in[21];  const float* be1  = (const float*)d_in[22];
  const float* g2   = (const float*)d_in[23];  const float* be2  = (const float*)d_in[24];
  const float* g3   = (const float*)d_in[25];  const float* be3  = (const float*)d_in[26];

  float* outV = (float*)d_out;                 // [2,1024,128]
  float* outE = outV + (size_t)BB * NN * HH;   // [2,1024,48,128]

  u16* ws     = (u16*)d_ws;
  u16* W1bT   = ws;
  u16* W11bT  = W1bT  + 3 * 16384;
  u16* W2t    = W11bT + 3 * 16384;
  u16* W3t    = W2t   + 3 * 16384;
  u16* W12t   = W3t   + 3 * 16384;
  u16* W13t   = W12t  + 3 * 16384;
  u16* Wint   = W13t  + 3 * 16384;
  u16* Woutt  = Wint  + 3 * 65536;
  u16* PREb   = Woutt + 3 * 65536;
  u16* hv0bf  = PREb  + 3 * 65536;
  u16* Pbf    = hv0bf + BB * NN * HH;
  float* Pf   = (float*)(Pbf + BB * NN * HH);
  float* Qf   = Pf  + BB * NN * HH;
  float* Qn   = Qf  + BB * NN * HH;
  float* Pn   = Qn  + BB * NN * HH;
  float* Qe   = Pn  + BB * NN * HH;
  float* Pe   = Qe  + BB * NN * HH;

  conv_weights<<<512, 256, 0, stream>>>(W1, W2, W3, W11, W12, W13, Win, Wout, h_V,
                                        W1bT, W2t, W3t, W11bT, W12t, W13t, Wint, Woutt,
                                        PREb, hv0bf);

  pre_kernel<<<(BB * NN) / 16, 256, 0, stream>>>(
      hv0bf, PREb + 2 * 65536 + 2 * 16384, PREb + 2 * 65536 + 3 * 16384, Qn, Pn);

  for (int l = 0; l < LL; ++l) {
    const float* hv_res  = (l == 0) ? h_V : Qf;
    const float* hE_src  = (l == 0) ? h_E : outE;
    float*       hv2_dst = (l == 2) ? outV : Qf;

    node_msg<<<BB * NN, 256, 0, stream>>>(
        hv_res, Qn, Pn, hE_src, E_idx, mask_att,
        W1bT + l * 16384, W2t + l * 16384, W3t + l * 16384,
        b1 + l * 128, b2 + l * 128, b3 + l * 128,
        g1 + l * 128, be1 + l * 128,
        Pf, Pbf);

    ffn_kernel<<<(BB * NN) / 8, 256, 0, stream>>>(
        Pf, Pbf,
        Wint + l * 65536, binp + l * 512,
        Woutt + l * 65536, boutp + l * 128,
        g2 + l * 128, be2 + l * 128, mask_V,
        PREb + l * 65536,
        hv2_dst, Qe, Pe, Qn, Pn);

    edge_kernel<<<BB * NN, 256, 0, stream>>>(
        Qe, Pe, hE_src, E_idx,
        W11bT + l * 16384, W12t + l * 16384, W13t + l * 16384,
        b11 + l * 128, b12 + l * 128, b13 + l * 128,
        g3 + l * 128, be3 + l * 128,
        outE);
  }
}

// Round 10
// 292.377 us; speedup vs baseline: 1.1774x; 1.0669x over previous
//
#include <hip/hip_runtime.h>
#include <hip/hip_bf16.h>
#include <math.h>

#define BB 2
#define NN 1024
#define HH 128
#define LL 3
#define SY 136   // LDS tile row stride (bf16 elems): 128+8
#define SH 520   // FFN hidden row stride
#define SX 136   // FFN input row stride
#define SM 132   // edge out f32 row stride

typedef __attribute__((ext_vector_type(8))) short s8v;   // 8 bf16
typedef __attribute__((ext_vector_type(4))) float f4v;   // MFMA acc
typedef unsigned short u16;

static __device__ __forceinline__ u16 f2bf(float x) {
  union { float f; unsigned u; } v; v.f = x;
  unsigned r = v.u + 0x7FFFu + ((v.u >> 16) & 1u);  // RNE
  return (u16)(r >> 16);
}
// fast tanh-form GELU (|err| vs erf-gelu ~3e-3)
static __device__ __forceinline__ float geluf(float x) {
  float x2 = x * x;
  float u2 = x * (1.5957691216f + 0.0713548163f * x2);
  float e = __expf(u2);
  float d = __builtin_amdgcn_rcpf(e + 1.0f);
  return x - x * d;
}

// ---- node-path helpers (validated) ----
static __device__ __forceinline__ void loadB(const u16* __restrict__ Wt, int wave, int lane,
                                             s8v B0[4], s8v B1[4]) {
  const int g = lane >> 4, q = lane & 15;
  const u16* wb0 = Wt + (wave * 32 + q) * 128 + g * 8;
  const u16* wb1 = wb0 + 16 * 128;
#pragma unroll
  for (int t = 0; t < 4; ++t) { B0[t] = *(const s8v*)(wb0 + t * 32); B1[t] = *(const s8v*)(wb1 + t * 32); }
}

static __device__ __forceinline__ void gemmA(const u16* __restrict__ A,
                                             const s8v B0[4], const s8v B1[4],
                                             int lane, f4v acc[3][2]) {
  const int g = lane >> 4, q = lane & 15;
  __builtin_amdgcn_s_setprio(1);
#pragma unroll
  for (int t = 0; t < 4; ++t) {
    const u16* Ab = A + t * 32 + g * 8;
    s8v a0 = *(const s8v*)(Ab + q * SY);
    s8v a1 = *(const s8v*)(Ab + (16 + q) * SY);
    s8v a2 = *(const s8v*)(Ab + (32 + q) * SY);
    acc[0][0] = __builtin_amdgcn_mfma_f32_16x16x32_bf16(a0, B0[t], acc[0][0], 0, 0, 0);
    acc[0][1] = __builtin_amdgcn_mfma_f32_16x16x32_bf16(a0, B1[t], acc[0][1], 0, 0, 0);
    acc[1][0] = __builtin_amdgcn_mfma_f32_16x16x32_bf16(a1, B0[t], acc[1][0], 0, 0, 0);
    acc[1][1] = __builtin_amdgcn_mfma_f32_16x16x32_bf16(a1, B1[t], acc[1][1], 0, 0, 0);
    acc[2][0] = __builtin_amdgcn_mfma_f32_16x16x32_bf16(a2, B0[t], acc[2][0], 0, 0, 0);
    acc[2][1] = __builtin_amdgcn_mfma_f32_16x16x32_bf16(a2, B1[t], acc[2][1], 0, 0, 0);
  }
  __builtin_amdgcn_s_setprio(0);
}

// ---- edge-path GEMM (R4/R8-validated: loadB inside, no setprio) ----
static __device__ __forceinline__ void gemm48k128(const u16* __restrict__ A,
                                                  const u16* __restrict__ Wt,
                                                  int wave, int lane, f4v acc[3][2]) {
  const int g = lane >> 4, q = lane & 15;
  s8v B0[4], B1[4];
  const u16* wb0 = Wt + (wave * 32 + q) * 128 + g * 8;
  const u16* wb1 = wb0 + 16 * 128;
#pragma unroll
  for (int t = 0; t < 4; ++t) { B0[t] = *(const s8v*)(wb0 + t * 32); B1[t] = *(const s8v*)(wb1 + t * 32); }
#pragma unroll
  for (int t = 0; t < 4; ++t) {
    const u16* Ab = A + t * 32 + g * 8;
    s8v a0 = *(const s8v*)(Ab + q * SY);
    s8v a1 = *(const s8v*)(Ab + (16 + q) * SY);
    s8v a2 = *(const s8v*)(Ab + (32 + q) * SY);
    acc[0][0] = __builtin_amdgcn_mfma_f32_16x16x32_bf16(a0, B0[t], acc[0][0], 0, 0, 0);
    acc[0][1] = __builtin_amdgcn_mfma_f32_16x16x32_bf16(a0, B1[t], acc[0][1], 0, 0, 0);
    acc[1][0] = __builtin_amdgcn_mfma_f32_16x16x32_bf16(a1, B0[t], acc[1][0], 0, 0, 0);
    acc[1][1] = __builtin_amdgcn_mfma_f32_16x16x32_bf16(a1, B1[t], acc[1][1], 0, 0, 0);
    acc[2][0] = __builtin_amdgcn_mfma_f32_16x16x32_bf16(a2, B0[t], acc[2][0], 0, 0, 0);
    acc[2][1] = __builtin_amdgcn_mfma_f32_16x16x32_bf16(a2, B1[t], acc[2][1], 0, 0, 0);
  }
}

static __device__ __forceinline__ void zero_acc(f4v acc[3][2]) {
#pragma unroll
  for (int rt = 0; rt < 3; ++rt)
#pragma unroll
    for (int c = 0; c < 2; ++c) acc[rt][c] = (f4v){0.f, 0.f, 0.f, 0.f};
}

// acc(+bias, gelu) -> LDS Y bf16 (stride SY). C layout: col=lane&15, row=(lane>>4)*4+r.
static __device__ __forceinline__ void store_act(const f4v acc[3][2], u16* __restrict__ Y,
                                                 int wave, int lane, const float* __restrict__ bias) {
  const int g = lane >> 4, q = lane & 15;
#pragma unroll
  for (int c = 0; c < 2; ++c) {
    const int col = wave * 32 + c * 16 + q;
    const float bv = bias[col];
#pragma unroll
    for (int rt = 0; rt < 3; ++rt)
#pragma unroll
      for (int r = 0; r < 4; ++r) {
        const int row = rt * 16 + g * 4 + r;
        Y[row * SY + col] = f2bf(geluf(acc[rt][c][r] + bv));
      }
  }
}

// stage hE f32 (48x128) -> bf16 LDS
static __device__ __forceinline__ void stage_f32(u16* __restrict__ dst, const float* src, int tid) {
  const float4* hEr = (const float4*)src;
#pragma unroll
  for (int p = 0; p < 6; ++p) {
    int i = tid + p * 256; int row = i >> 5, c = i & 31;
    float4 v = hEr[i];
    uint2 pk;
    pk.x = (unsigned)f2bf(v.x) | ((unsigned)f2bf(v.y) << 16);
    pk.y = (unsigned)f2bf(v.z) | ((unsigned)f2bf(v.w) << 16);
    *(uint2*)(dst + row * SY + c * 4) = pk;
  }
}

// acc init = Q[bid][col] + P[gather(row)][col]  (node path; reads eidx directly)
static __device__ __forceinline__ void init_acc(f4v acc[3][2],
                                                const float* __restrict__ Q, const float* __restrict__ P,
                                                const int* __restrict__ eidx, int bid, int bbase,
                                                int wave, int g, int q) {
  const float* Qr = Q + (size_t)bid * 128;
  const float qv0 = Qr[wave * 32 + q];
  const float qv1 = Qr[wave * 32 + 16 + q];
#pragma unroll
  for (int rt = 0; rt < 3; ++rt)
#pragma unroll
    for (int r = 0; r < 4; ++r) {
      const int row = rt * 16 + g * 4 + r;
      const int idx = eidx[bid * 48 + row];
      const float* Pr = P + (size_t)(bbase + idx) * 128 + wave * 32;
      acc[rt][0][r] = qv0 + Pr[q];
      acc[rt][1][r] = qv1 + Pr[16 + q];
    }
}

// ---------------- weight/hv convert ----------------
// PRE_l [512][128]: rows 0-127 W11aT(l), 128-255 W11cT(l), 256-383 W1aT((l+1)%3), 384-511 W1cT((l+1)%3)
__global__ void conv_weights(const float* __restrict__ W1, const float* __restrict__ W2,
                             const float* __restrict__ W3, const float* __restrict__ W11,
                             const float* __restrict__ W12, const float* __restrict__ W13,
                             const float* __restrict__ Win, const float* __restrict__ Wout,
                             const float* __restrict__ hV,
                             u16* __restrict__ W1bT, u16* __restrict__ W2t,
                             u16* __restrict__ W3t, u16* __restrict__ W11bT,
                             u16* __restrict__ W12t, u16* __restrict__ W13t,
                             u16* __restrict__ Wint, u16* __restrict__ Woutt,
                             u16* __restrict__ PRE, u16* __restrict__ hv0bf) {
  const int tid = blockIdx.x * blockDim.x + threadIdx.x;
  const int nt = gridDim.x * blockDim.x;
  for (int i = tid; i < LL * 128 * 128; i += nt) {
    int l = i >> 14, rem = i & 16383;
    int k = rem >> 7, n = rem & 127;
    const int o = (l * 128 + n) * 128 + k;
    const int s = l * 16384 + k * 128 + n;
    W1bT [o] = f2bf(W1 [l * 49152 + (128 + k) * 128 + n]);
    W11bT[o] = f2bf(W11[l * 49152 + (128 + k) * 128 + n]);
    W2t [o] = f2bf(W2 [s]);
    W3t [o] = f2bf(W3 [s]);
    W12t[o] = f2bf(W12[s]);
    W13t[o] = f2bf(W13[s]);
    const int ln = (l + 1 == LL) ? 0 : l + 1;
    PRE[l * 65536 + (0 * 128 + n) * 128 + k] = f2bf(W11[l * 49152 + k * 128 + n]);
    PRE[l * 65536 + (1 * 128 + n) * 128 + k] = f2bf(W11[l * 49152 + (256 + k) * 128 + n]);
    PRE[l * 65536 + (2 * 128 + n) * 128 + k] = f2bf(W1 [ln * 49152 + k * 128 + n]);
    PRE[l * 65536 + (3 * 128 + n) * 128 + k] = f2bf(W1 [ln * 49152 + (256 + k) * 128 + n]);
  }
  for (int i = tid; i < LL * 128 * 512; i += nt) {
    int l = i / (128 * 512), rem = i - l * 128 * 512;
    int k = rem / 512, u = rem - k * 512;
    Wint[(l * 512 + u) * 128 + k] = f2bf(Win[i]);
  }
  for (int i = tid; i < LL * 512 * 128; i += nt) {
    int l = i / (512 * 128), rem = i - l * 512 * 128;
    int k = rem / 128, n = rem - k * 128;
    Woutt[(l * 128 + n) * 512 + k] = f2bf(Wout[i]);
  }
  for (int i = tid; i < BB * NN * HH; i += nt) hv0bf[i] = f2bf(hV[i]);
}

// ---------------- layer-0 node pre: Q = hv@W1a, P = hv@W1c ----------------
__global__ __launch_bounds__(256) void pre_kernel(const u16* __restrict__ hvbf,
                                                  const u16* __restrict__ Wq,
                                                  const u16* __restrict__ Wp,
                                                  float* __restrict__ Q, float* __restrict__ P) {
  __shared__ __align__(16) u16 shX[16 * SX];
  const int tid = threadIdx.x, lane = tid & 63, wave = tid >> 6;
  const int g = lane >> 4, q = lane & 15;
  const int r0 = blockIdx.x * 16;
  { int row = tid >> 4, c = tid & 15;
    *(uint4*)(shX + row * SX + c * 8) = ((const uint4*)(hvbf + (size_t)r0 * 128))[tid]; }
  __syncthreads();
  s8v af[4];
#pragma unroll
  for (int t = 0; t < 4; ++t) af[t] = *(const s8v*)(shX + q * SX + t * 32 + g * 8);
  const u16* W = (wave < 2) ? Wq : Wp;
  float* D = (wave < 2) ? Q : P;
  const int c0 = (wave & 1) * 64;
#pragma unroll
  for (int cf = 0; cf < 4; ++cf) {
    const int col = c0 + cf * 16 + q;
    const u16* wb = W + (size_t)col * 128 + g * 8;
    f4v acc = (f4v){0.f, 0.f, 0.f, 0.f};
#pragma unroll
    for (int t = 0; t < 4; ++t)
      acc = __builtin_amdgcn_mfma_f32_16x16x32_bf16(af[t], *(const s8v*)(wb + t * 32), acc, 0, 0, 0);
#pragma unroll
    for (int r = 0; r < 4; ++r) D[(size_t)(r0 + g * 4 + r) * 128 + col] = acc[r];
  }
}

// ---------------- node message (validated) ----------------
__global__ __launch_bounds__(256, 6) void node_msg(
    const float* __restrict__ hv_res, const float* __restrict__ Qn, const float* __restrict__ Pn,
    const float* hE_src, const int* __restrict__ eidx, const float* __restrict__ mask_att,
    const u16* __restrict__ W1bT, const u16* __restrict__ W2t, const u16* __restrict__ W3t,
    const float* __restrict__ b1, const float* __restrict__ b2, const float* __restrict__ b3,
    const float* __restrict__ g1, const float* __restrict__ be1,
    float* __restrict__ hv1, u16* __restrict__ hv1bf) {
  __shared__ __align__(16) u16 buf[2 * 48 * SY];
  __shared__ float sh_mask[48];
  __shared__ float sh_x[128];
  __shared__ float sh_st[2];
  u16* bufA = buf;
  u16* bufB = buf + 48 * SY;

  const int tid = threadIdx.x, lane = tid & 63, wave = tid >> 6;
  const int g = lane >> 4, q = lane & 15;
  const int bid = blockIdx.x, bbase = bid & ~(NN - 1);

  if (tid < 48) sh_mask[tid] = mask_att[bid * 48 + tid];
  f4v acc[3][2];
  init_acc(acc, Qn, Pn, eidx, bid, bbase, wave, g, q);
  stage_f32(bufA, hE_src + (size_t)bid * 6144, tid);
  s8v Ba[4], Bb[4];
  loadB(W1bT, wave, lane, Ba, Bb);
  __syncthreads();

  gemmA(bufA, Ba, Bb, lane, acc);
  loadB(W2t, wave, lane, Ba, Bb);
  store_act(acc, bufB, wave, lane, b1);
  __syncthreads();

  zero_acc(acc);
  gemmA(bufB, Ba, Bb, lane, acc);
  loadB(W3t, wave, lane, Ba, Bb);
  store_act(acc, bufA, wave, lane, b2);
  __syncthreads();

  zero_acc(acc);
  gemmA(bufA, Ba, Bb, lane, acc);

  float msum = 0.f;
#pragma unroll
  for (int k = 0; k < 48; ++k) msum += sh_mask[k];
  float p0 = 0.f, p1 = 0.f;
#pragma unroll
  for (int rt = 0; rt < 3; ++rt)
#pragma unroll
    for (int r = 0; r < 4; ++r) {
      const float mk = sh_mask[rt * 16 + g * 4 + r];
      p0 += acc[rt][0][r] * mk;
      p1 += acc[rt][1][r] * mk;
    }
  p0 += __shfl_xor(p0, 16); p0 += __shfl_xor(p0, 32);
  p1 += __shfl_xor(p1, 16); p1 += __shfl_xor(p1, 32);
  if (g == 0) {
    const int c0 = wave * 32 + q, c1 = wave * 32 + 16 + q;
    sh_x[c0] = hv_res[(size_t)bid * 128 + c0] + (p0 + b3[c0] * msum) * (1.f / 30.f);
    sh_x[c1] = hv_res[(size_t)bid * 128 + c1] + (p1 + b3[c1] * msum) * (1.f / 30.f);
  }
  __syncthreads();

  if (tid < 64) {
    float a = sh_x[tid], c2 = sh_x[tid + 64];
    float s = a + c2, ss = a * a + c2 * c2;
#pragma unroll
    for (int off = 32; off; off >>= 1) { s += __shfl_xor(s, off); ss += __shfl_xor(ss, off); }
    if (tid == 0) { float mu = s * (1.f / 128.f); sh_st[0] = mu; sh_st[1] = ss * (1.f / 128.f) - mu * mu; }
  }
  __syncthreads();
  if (tid < 128) {
    float mu = sh_st[0], rs = rsqrtf(sh_st[1] + 1e-5f);
    float v = g1[tid] * (sh_x[tid] - mu) * rs + be1[tid];
    hv1[(size_t)bid * 128 + tid] = v;
    hv1bf[(size_t)bid * 128 + tid] = f2bf(v);
  }
}

// ---------------- FFN + LN2 + mask + fused pre-products (validated) ----------------
__global__ __launch_bounds__(256) void ffn_kernel(
    const float* __restrict__ hv1, const u16* __restrict__ hv1bf,
    const u16* __restrict__ Wint, const float* __restrict__ binp,
    const u16* __restrict__ Woutt, const float* __restrict__ boutp,
    const float* __restrict__ g2, const float* __restrict__ be2,
    const float* __restrict__ mask_V,
    const u16* __restrict__ PRE,
    float* __restrict__ hv2,
    float* __restrict__ Qe, float* __restrict__ Pe,
    float* __restrict__ QnN, float* __restrict__ PnN) {
  __shared__ __align__(16) u16 shX[16 * SX];
  __shared__ __align__(16) u16 shH[16 * SH];
  __shared__ float shM[8 * 128];
  const int tid = threadIdx.x, lane = tid & 63, wave = tid >> 6;
  const int g = lane >> 4, q = lane & 15;
  const int r0 = blockIdx.x * 8;

  {
    int row = tid >> 4, c = tid & 15;
    uint4 v = (uint4){0, 0, 0, 0};
    if (tid < 128) v = ((const uint4*)(hv1bf + (size_t)r0 * 128))[tid];
    *(uint4*)(shX + row * SX + c * 8) = v;
  }
  __syncthreads();

  s8v a[4];
#pragma unroll
  for (int t = 0; t < 4; ++t) a[t] = *(const s8v*)(shX + q * SX + t * 32 + g * 8);
#pragma unroll
  for (int cf = 0; cf < 8; ++cf) {
    const int u = wave * 128 + cf * 16 + q;
    const u16* wb = Wint + (size_t)u * 128 + g * 8;
    f4v acc = (f4v){0.f, 0.f, 0.f, 0.f};
#pragma unroll
    for (int t = 0; t < 4; ++t)
      acc = __builtin_amdgcn_mfma_f32_16x16x32_bf16(a[t], *(const s8v*)(wb + t * 32), acc, 0, 0, 0);
    const float bv = binp[u];
#pragma unroll
    for (int r = 0; r < 4; ++r) shH[(g * 4 + r) * SH + u] = f2bf(geluf(acc[r] + bv));
  }
  __syncthreads();

#pragma unroll
  for (int c = 0; c < 2; ++c) {
    const int col = wave * 32 + c * 16 + q;
    const u16* wb = Woutt + (size_t)col * 512 + g * 8;
    s8v Bv[16];
#pragma unroll
    for (int t = 0; t < 16; ++t) Bv[t] = *(const s8v*)(wb + t * 32);
    f4v acc = (f4v){0.f, 0.f, 0.f, 0.f};
#pragma unroll
    for (int t = 0; t < 16; ++t) {
      s8v av = *(const s8v*)(shH + q * SH + t * 32 + g * 8);
      acc = __builtin_amdgcn_mfma_f32_16x16x32_bf16(av, Bv[t], acc, 0, 0, 0);
    }
    const float bv = boutp[col];
#pragma unroll
    for (int r = 0; r < 4; ++r) {
      const int row = g * 4 + r;
      if (row < 8) shM[row * 128 + col] = acc[r] + bv;
    }
  }
  __syncthreads();

#pragma unroll
  for (int i = 0; i < 2; ++i) {
    const int row = wave * 2 + i, gr = r0 + row;
    float x0 = hv1[(size_t)gr * 128 + lane]      + shM[row * 128 + lane];
    float x1 = hv1[(size_t)gr * 128 + 64 + lane] + shM[row * 128 + 64 + lane];
    float s = x0 + x1, ss = x0 * x0 + x1 * x1;
#pragma unroll
    for (int off = 32; off; off >>= 1) { s += __shfl_xor(s, off); ss += __shfl_xor(ss, off); }
    const float mu = s * (1.f / 128.f);
    const float rs = rsqrtf(ss * (1.f / 128.f) - mu * mu + 1e-5f);
    const float mv = mask_V[gr];
    float o0 = mv * (g2[lane]      * (x0 - mu) * rs + be2[lane]);
    float o1 = mv * (g2[lane + 64] * (x1 - mu) * rs + be2[lane + 64]);
    hv2[(size_t)gr * 128 + lane] = o0;
    hv2[(size_t)gr * 128 + 64 + lane] = o1;
    shX[row * SX + lane] = f2bf(o0);
    shX[row * SX + 64 + lane] = f2bf(o1);
  }
  __syncthreads();

  s8v af[4];
#pragma unroll
  for (int t = 0; t < 4; ++t) af[t] = *(const s8v*)(shX + q * SX + t * 32 + g * 8);
  float* dst = (wave == 0) ? Qe : (wave == 1) ? Pe : (wave == 2) ? QnN : PnN;
  const u16* Wb = PRE + (size_t)(wave * 128) * 128;
#pragma unroll
  for (int cf = 0; cf < 8; ++cf) {
    const int colr = cf * 16 + q;
    const u16* wb = Wb + (size_t)colr * 128 + g * 8;
    f4v acc = (f4v){0.f, 0.f, 0.f, 0.f};
#pragma unroll
    for (int t = 0; t < 4; ++t)
      acc = __builtin_amdgcn_mfma_f32_16x16x32_bf16(af[t], *(const s8v*)(wb + t * 32), acc, 0, 0, 0);
    if (g < 2) {
#pragma unroll
      for (int r = 0; r < 4; ++r)
        dst[(size_t)(r0 + g * 4 + r) * 128 + colr] = acc[r];
    }
  }
}

// ---------------- edge update: R8 body + R5-proven register LN3 + LDS-bounced coalesced write ----------------
__global__ __launch_bounds__(256, 5) void edge_kernel(
    const float* __restrict__ Qe, const float* __restrict__ Pe,
    const float* hE_src, const int* __restrict__ eidx,
    const u16* __restrict__ W11bT, const u16* __restrict__ W12t, const u16* __restrict__ W13t,
    const float* __restrict__ b11, const float* __restrict__ b12, const float* __restrict__ b13,
    const float* __restrict__ g3, const float* __restrict__ be3,
    float* hE_out) {
  __shared__ __align__(16) u16 buf[2 * 48 * SY];
  __shared__ float2 sh_stats[48 * 4];
  __shared__ float2 sh_statsF[48];
  __shared__ int sh_idx[48];
  u16* bufA = buf;
  u16* bufB = buf + 48 * SY;

  const int tid = threadIdx.x, lane = tid & 63, wave = tid >> 6;
  const int g = lane >> 4, q = lane & 15;
  const int bid = blockIdx.x, bbase = bid & ~(NN - 1);

  if (tid < 48) sh_idx[tid] = eidx[bid * 48 + tid];
  stage_f32(bufA, hE_src + (size_t)bid * 6144, tid);
  __syncthreads();

  f4v acc[3][2];
  {
    const float* Qr = Qe + (size_t)bid * 128;
#pragma unroll
    for (int c = 0; c < 2; ++c) {
      const int col = wave * 32 + c * 16 + q;
      const float qv = Qr[col];
#pragma unroll
      for (int rt = 0; rt < 3; ++rt)
#pragma unroll
        for (int r = 0; r < 4; ++r) {
          const int row = rt * 16 + g * 4 + r;
          acc[rt][c][r] = qv + Pe[(size_t)(bbase + sh_idx[row]) * 128 + col];
        }
    }
  }
  gemm48k128(bufA, W11bT, wave, lane, acc);
  store_act(acc, bufB, wave, lane, b11);
  __syncthreads();

  zero_acc(acc);
  gemm48k128(bufB, W12t, wave, lane, acc);
  store_act(acc, bufA, wave, lane, b12);
  __syncthreads();

  // residual preload in acc layout (R5-proven), then GEMM3
  const float* heb = hE_src + (size_t)bid * 6144;
  float xh[3][2][4];
#pragma unroll
  for (int rt = 0; rt < 3; ++rt)
#pragma unroll
    for (int c = 0; c < 2; ++c)
#pragma unroll
      for (int r = 0; r < 4; ++r)
        xh[rt][c][r] = heb[(rt * 16 + g * 4 + r) * 128 + wave * 32 + c * 16 + q];
  zero_acc(acc);
  gemm48k128(bufA, W13t, wave, lane, acc);
  const float bv0 = b13[wave * 32 + q], bv1 = b13[wave * 32 + 16 + q];
#pragma unroll
  for (int rt = 0; rt < 3; ++rt)
#pragma unroll
    for (int r = 0; r < 4; ++r) {
      xh[rt][0][r] += acc[rt][0][r] + bv0;
      xh[rt][1][r] += acc[rt][1][r] + bv1;
    }

  // per-row stats: q-group reduce (R5-proven) + cross-wave combine in small dedicated LDS
#pragma unroll
  for (int rt = 0; rt < 3; ++rt)
#pragma unroll
    for (int r = 0; r < 4; ++r) {
      float s = xh[rt][0][r] + xh[rt][1][r];
      float ss = xh[rt][0][r] * xh[rt][0][r] + xh[rt][1][r] * xh[rt][1][r];
#pragma unroll
      for (int off = 1; off < 16; off <<= 1) { s += __shfl_xor(s, off); ss += __shfl_xor(ss, off); }
      if (q == 0) sh_stats[(rt * 16 + g * 4 + r) * 4 + wave] = make_float2(s, ss);
    }
  __syncthreads();                       // also guarantees all gemm3 bufA reads complete
  if (tid < 48) {
    float s = 0.f, ss = 0.f;
#pragma unroll
    for (int w = 0; w < 4; ++w) { float2 v = sh_stats[tid * 4 + w]; s += v.x; ss += v.y; }
    float mu = s * (1.f / 128.f);
    float rs = rsqrtf(ss * (1.f / 128.f) - mu * mu + 1e-5f);
    sh_statsF[tid] = make_float2(mu, rs);
  }
  __syncthreads();

  // normalize in registers, bounce through LDS (buf is dead), coalesced float4 write-out
  float* shOut = (float*)buf;            // 48*SM*4 = 25344 B <= 26112 B
  const float g30 = g3[wave * 32 + q], g31 = g3[wave * 32 + 16 + q];
  const float be30 = be3[wave * 32 + q], be31 = be3[wave * 32 + 16 + q];
#pragma unroll
  for (int rt = 0; rt < 3; ++rt)
#pragma unroll
    for (int r = 0; r < 4; ++r) {
      const int row = rt * 16 + g * 4 + r;
      const float2 mf = sh_statsF[row];
      shOut[row * SM + wave * 32 + q]      = g30 * (xh[rt][0][r] - mf.x) * mf.y + be30;
      shOut[row * SM + wave * 32 + 16 + q] = g31 * (xh[rt][1][r] - mf.x) * mf.y + be31;
    }
  __syncthreads();

  float4* wdst = (float4*)(hE_out + (size_t)bid * 6144);
#pragma unroll
  for (int p = 0; p < 6; ++p) {
    const int i = tid + p * 256;
    const int row = i >> 5, c4 = i & 31;
    wdst[i] = *(const float4*)(shOut + row * SM + 4 * c4);
  }
}

extern "C" void kernel_launch(void* const* d_in, const int* in_sizes, int n_in,
                              void* d_out, int out_size, void* d_ws, size_t ws_size,
                              hipStream_t stream) {
  const float* h_V      = (const float*)d_in[0];
  const float* h_E      = (const float*)d_in[1];
  const int*   E_idx    = (const int*)d_in[2];
  const float* mask_V   = (const float*)d_in[3];
  const float* mask_att = (const float*)d_in[4];
  const float* W1   = (const float*)d_in[5];   const float* b1   = (const float*)d_in[6];
  const float* W2   = (const float*)d_in[7];   const float* b2   = (const float*)d_in[8];
  const float* W3   = (const float*)d_in[9];   const float* b3   = (const float*)d_in[10];
  const float* W11  = (const float*)d_in[11];  const float* b11  = (const float*)d_in[12];
  const float* W12  = (const float*)d_in[13];  const float* b12  = (const float*)d_in[14];
  const float* W13  = (const float*)d_in[15];  const float* b13  = (const float*)d_in[16];
  const float* Win  = (const float*)d_in[17];  const float* binp = (const float*)d_in[18];
  const float* Wout = (const float*)d_in[19];  const float* boutp= (const float*)d_in[20];
  const float* g1   = (const float*)d_in[21];  const float* be1  = (const float*)d_in[22];
  const float* g2   = (const float*)d_in[23];  const float* be2  = (const float*)d_in[24];
  const float* g3   = (const float*)d_in[25];  const float* be3  = (const float*)d_in[26];

  float* outV = (float*)d_out;                 // [2,1024,128]
  float* outE = outV + (size_t)BB * NN * HH;   // [2,1024,48,128]

  u16* ws     = (u16*)d_ws;
  u16* W1bT   = ws;
  u16* W11bT  = W1bT  + 3 * 16384;
  u16* W2t    = W11bT + 3 * 16384;
  u16* W3t    = W2t   + 3 * 16384;
  u16* W12t   = W3t   + 3 * 16384;
  u16* W13t   = W12t  + 3 * 16384;
  u16* Wint   = W13t  + 3 * 16384;
  u16* Woutt  = Wint  + 3 * 65536;
  u16* PREb   = Woutt + 3 * 65536;
  u16* hv0bf  = PREb  + 3 * 65536;
  u16* Pbf    = hv0bf + BB * NN * HH;
  float* Pf   = (float*)(Pbf + BB * NN * HH);
  float* Qf   = Pf  + BB * NN * HH;
  float* Qn   = Qf  + BB * NN * HH;
  float* Pn   = Qn  + BB * NN * HH;
  float* Qe   = Pn  + BB * NN * HH;
  float* Pe   = Qe  + BB * NN * HH;

  conv_weights<<<512, 256, 0, stream>>>(W1, W2, W3, W11, W12, W13, Win, Wout, h_V,
                                        W1bT, W2t, W3t, W11bT, W12t, W13t, Wint, Woutt,
                                        PREb, hv0bf);

  pre_kernel<<<(BB * NN) / 16, 256, 0, stream>>>(
      hv0bf, PREb + 2 * 65536 + 2 * 16384, PREb + 2 * 65536 + 3 * 16384, Qn, Pn);

  for (int l = 0; l < LL; ++l) {
    const float* hv_res  = (l == 0) ? h_V : Qf;
    const float* hE_src  = (l == 0) ? h_E : outE;
    float*       hv2_dst = (l == 2) ? outV : Qf;

    node_msg<<<BB * NN, 256, 0, stream>>>(
        hv_res, Qn, Pn, hE_src, E_idx, mask_att,
        W1bT + l * 16384, W2t + l * 16384, W3t + l * 16384,
        b1 + l * 128, b2 + l * 128, b3 + l * 128,
        g1 + l * 128, be1 + l * 128,
        Pf, Pbf);

    ffn_kernel<<<(BB * NN) / 8, 256, 0, stream>>>(
        Pf, Pbf,
        Wint + l * 65536, binp + l * 512,
        Woutt + l * 65536, boutp + l * 128,
        g2 + l * 128, be2 + l * 128, mask_V,
        PREb + l * 65536,
        hv2_dst, Qe, Pe, Qn, Pn);

    edge_kernel<<<BB * NN, 256, 0, stream>>>(
        Qe, Pe, hE_src, E_idx,
        W11bT + l * 16384, W12t + l * 16384, W13t + l * 16384,
        b11 + l * 128, b12 + l * 128, b13 + l * 128,
        g3 + l * 128, be3 + l * 128,
        outE);
  }
}